// Round 3
// 499.717 us; speedup vs baseline: 1.0159x; 1.0159x over previous
//
#include <hip/hip_runtime.h>
#include <cstddef>

// Shapes
constexpr int H  = 256;
constexpr int Bb = 128;
constexpr int T  = 2048;
constexpr int V  = 32000;
constexpr int SPLITS = 16;          // T-chunks for attention pass
constexpr int TC = T / SPLITS;      // 128 timesteps per block (32 per wave)
constexpr int NPART = SPLITS * 4;   // 64 ctx partials per b (per wave)
constexpr int NBLK = V / 128;       // 250 logits blocks -> LSE partials per row

typedef __attribute__((ext_vector_type(8))) short short8;
typedef __attribute__((ext_vector_type(4))) float f32x4;

// round-to-nearest-even fp32 -> bf16 (inputs are finite)
__device__ __forceinline__ unsigned short bf1(float a) {
  unsigned u = __builtin_bit_cast(unsigned, a);
  return (unsigned short)((u + 0x7fffu + ((u >> 16) & 1u)) >> 16);
}
__device__ __forceinline__ unsigned bfpack2(float a, float b) {
  unsigned ua = __builtin_bit_cast(unsigned, a);
  unsigned ub = __builtin_bit_cast(unsigned, b);
  ua = (ua + 0x7fffu + ((ua >> 16) & 1u)) >> 16;
  ub = (ub + 0x7fffu + ((ub >> 16) & 1u)) & 0xffff0000u;
  return ua | ub;
}

// ---------------------------------------------------------------------------
// K1: fused scores + unnormalized ctx partials. One pass over enc (256 MB).
// grid (SPLITS, B), block 256 = 4 waves. Wave owns 32 consecutive t.
// HBM-bound by construction (enc read exactly once).
// ---------------------------------------------------------------------------
__global__ __launch_bounds__(256) void k_attn(
    const float* __restrict__ enc, const float* __restrict__ hidden,
    const float* __restrict__ attn_W, const float* __restrict__ attn_b,
    float* __restrict__ scores, float* __restrict__ ctx_part) {
  const int b = blockIdx.y, chunk = blockIdx.x;
  const int tid = threadIdx.x, lane = tid & 63, wave = tid >> 6;

  const float4 we = *(const float4*)(attn_W + H + lane * 4);
  const float4 wh = *(const float4*)(attn_W + lane * 4);
  const float4 hv = *(const float4*)(hidden + (size_t)b * H + lane * 4);

  float hb = fmaf(wh.x, hv.x, fmaf(wh.y, hv.y, fmaf(wh.z, hv.z, wh.w * hv.w)));
  #pragma unroll
  for (int off = 1; off < 64; off <<= 1) hb += __shfl_xor(hb, off);
  hb += attn_b[0];

  const int t0 = chunk * TC + wave * 32;
  const float* base = enc + (size_t)t0 * (Bb * H) + (size_t)b * H + lane * 4;

  float4 acc = {0.f, 0.f, 0.f, 0.f};
  for (int i = 0; i < 32; i += 4) {
    float4 e0 = *(const float4*)(base + (size_t)(i + 0) * (Bb * H));
    float4 e1 = *(const float4*)(base + (size_t)(i + 1) * (Bb * H));
    float4 e2 = *(const float4*)(base + (size_t)(i + 2) * (Bb * H));
    float4 e3 = *(const float4*)(base + (size_t)(i + 3) * (Bb * H));

    float p0 = fmaf(e0.x, we.x, fmaf(e0.y, we.y, fmaf(e0.z, we.z, e0.w * we.w)));
    float p1 = fmaf(e1.x, we.x, fmaf(e1.y, we.y, fmaf(e1.z, we.z, e1.w * we.w)));
    float p2 = fmaf(e2.x, we.x, fmaf(e2.y, we.y, fmaf(e2.z, we.z, e2.w * we.w)));
    float p3 = fmaf(e3.x, we.x, fmaf(e3.y, we.y, fmaf(e3.z, we.z, e3.w * we.w)));
    #pragma unroll
    for (int off = 1; off < 64; off <<= 1) {
      p0 += __shfl_xor(p0, off);
      p1 += __shfl_xor(p1, off);
      p2 += __shfl_xor(p2, off);
      p3 += __shfl_xor(p3, off);
    }
    float s0 = p0 + hb, s1 = p1 + hb, s2 = p2 + hb, s3 = p3 + hb;
    float w0 = __expf(s0), w1 = __expf(s1), w2 = __expf(s2), w3 = __expf(s3);

    acc.x = fmaf(w0, e0.x, fmaf(w1, e1.x, fmaf(w2, e2.x, fmaf(w3, e3.x, acc.x))));
    acc.y = fmaf(w0, e0.y, fmaf(w1, e1.y, fmaf(w2, e2.y, fmaf(w3, e3.y, acc.y))));
    acc.z = fmaf(w0, e0.z, fmaf(w1, e1.z, fmaf(w2, e2.z, fmaf(w3, e3.z, acc.z))));
    acc.w = fmaf(w0, e0.w, fmaf(w1, e1.w, fmaf(w2, e2.w, fmaf(w3, e3.w, acc.w))));

    if (lane == 0) {
      float4 sv = {s0, s1, s2, s3};
      *(float4*)(scores + (size_t)b * T + t0 + i) = sv;
    }
  }
  float* cp = ctx_part + ((size_t)b * NPART + chunk * 4 + wave) * H + lane * 4;
  *(float4*)cp = acc;
}

// ---------------------------------------------------------------------------
// K2 (fused, was k_softmax_ctx + k_comb_gru): exact softmax -> attn_w + ctx,
// then emb/comb/ReLU/GRU on the same block with ctx passed through LDS.
// grid B, block 256 = 4 waves.
// GEMVs use a quad-split layout: 4 lanes share one weight row, so each
// wave-load is 16 x 64B contiguous segments (vs 64 x 16B scatter before),
// and the reduction is 2 shfl_xor stages instead of a per-thread 512-FMA
// uncoalesced walk.
// ---------------------------------------------------------------------------
__global__ __launch_bounds__(256) void k_ctx_gru(
    const float* __restrict__ scores, const float* __restrict__ ctx_part,
    float* __restrict__ attn_o, float* __restrict__ ctx_o,
    const int* __restrict__ tokens, const float* __restrict__ hidden,
    const float* __restrict__ emb_table,
    const float* __restrict__ comb_W, const float* __restrict__ comb_b,
    const float* __restrict__ Wih, const float* __restrict__ Whh,
    const float* __restrict__ bih, const float* __restrict__ bhh,
    float* __restrict__ hnew, unsigned short* __restrict__ hnewb) {
  const int b = blockIdx.x, tid = threadIdx.x;
  const int lane = tid & 63, wave = tid >> 6;
  const int g4 = lane >> 2, l4 = lane & 3;   // quad-split: 16 rows x 4 lanes
  __shared__ float red[4];
  __shared__ float m_sh, l_sh;
  __shared__ __align__(16) float x2[2 * H];
  __shared__ __align__(16) float hid[H];
  __shared__ __align__(16) float xs[H];
  __shared__ float Ar[H], Az[H], Cn[H], Dn[H];

  // ---- phase A: softmax over scores + ctx combine ----
  const float* sb = scores + (size_t)b * T;
  float s[8];
  #pragma unroll
  for (int q = 0; q < 8; q++) s[q] = sb[tid + 256 * q];

  float mx = s[0];
  #pragma unroll
  for (int q = 1; q < 8; q++) mx = fmaxf(mx, s[q]);
  #pragma unroll
  for (int off = 1; off < 64; off <<= 1) mx = fmaxf(mx, __shfl_xor(mx, off));
  if (lane == 0) red[wave] = mx;
  __syncthreads();
  if (tid == 0) m_sh = fmaxf(fmaxf(red[0], red[1]), fmaxf(red[2], red[3]));
  __syncthreads();
  const float m = m_sh;

  float w[8];
  float ps = 0.f;
  #pragma unroll
  for (int q = 0; q < 8; q++) { w[q] = __expf(s[q] - m); ps += w[q]; }
  #pragma unroll
  for (int off = 1; off < 64; off <<= 1) ps += __shfl_xor(ps, off);
  __syncthreads();
  if (lane == 0) red[wave] = ps;
  __syncthreads();
  if (tid == 0) l_sh = red[0] + red[1] + red[2] + red[3];
  __syncthreads();
  const float inv = 1.f / l_sh;

  #pragma unroll
  for (int q = 0; q < 8; q++) attn_o[(size_t)b * T + tid + 256 * q] = w[q] * inv;

  float c = 0.f;
  for (int si = 0; si < NPART; si++)
    c += ctx_part[((size_t)b * NPART + si) * H + tid];
  const float cval = c * __expf(-m) * inv;
  ctx_o[(size_t)b * H + tid] = cval;

  // stage inputs for phase B/C
  x2[tid]     = emb_table[(size_t)tokens[b] * H + tid];
  x2[H + tid] = cval;
  hid[tid]    = hidden[(size_t)b * H + tid];
  __syncthreads();

  // ---- phase B: comb linear + ReLU (quad-split GEMV, K=512) ----
  #pragma unroll 1
  for (int batch = 0; batch < 4; batch++) {
    const int row = wave * 64 + batch * 16 + g4;
    const float* wr = comb_W + (size_t)row * (2 * H);
    float p = 0.f;
    #pragma unroll 8
    for (int i = 0; i < 32; i++) {
      const int o = i * 16 + l4 * 4;
      float4 wv = *(const float4*)(wr + o);
      float4 xv = *(const float4*)(x2 + o);   // 16-way broadcast groups: free
      p = fmaf(wv.x, xv.x, fmaf(wv.y, xv.y, fmaf(wv.z, xv.z, fmaf(wv.w, xv.w, p))));
    }
    p += __shfl_xor(p, 1);
    p += __shfl_xor(p, 2);
    if (l4 == 0) xs[row] = fmaxf(p + comb_b[row], 0.f);
  }
  __syncthreads();

  // ---- phase C: 6 GRU gate GEMVs (quad-split, K=256) ----
  #pragma unroll 1
  for (int batch = 0; batch < 4; batch++) {
    const int row = wave * 64 + batch * 16 + g4;
    const float* wxr = Wih + (size_t)row * H;
    const float* wxz = Wih + (size_t)(row + H) * H;
    const float* wxn = Wih + (size_t)(row + 2 * H) * H;
    const float* whr = Whh + (size_t)row * H;
    const float* whz = Whh + (size_t)(row + H) * H;
    const float* whn = Whh + (size_t)(row + 2 * H) * H;
    float pxr = 0.f, pxz = 0.f, pxn = 0.f, phr = 0.f, phz = 0.f, phn = 0.f;
    #pragma unroll 2
    for (int i = 0; i < 16; i++) {
      const int o = i * 16 + l4 * 4;
      float4 xv = *(const float4*)(xs + o);
      float4 hv = *(const float4*)(hid + o);
      float4 a;
      a = *(const float4*)(wxr + o);
      pxr = fmaf(a.x, xv.x, fmaf(a.y, xv.y, fmaf(a.z, xv.z, fmaf(a.w, xv.w, pxr))));
      a = *(const float4*)(wxz + o);
      pxz = fmaf(a.x, xv.x, fmaf(a.y, xv.y, fmaf(a.z, xv.z, fmaf(a.w, xv.w, pxz))));
      a = *(const float4*)(wxn + o);
      pxn = fmaf(a.x, xv.x, fmaf(a.y, xv.y, fmaf(a.z, xv.z, fmaf(a.w, xv.w, pxn))));
      a = *(const float4*)(whr + o);
      phr = fmaf(a.x, hv.x, fmaf(a.y, hv.y, fmaf(a.z, hv.z, fmaf(a.w, hv.w, phr))));
      a = *(const float4*)(whz + o);
      phz = fmaf(a.x, hv.x, fmaf(a.y, hv.y, fmaf(a.z, hv.z, fmaf(a.w, hv.w, phz))));
      a = *(const float4*)(whn + o);
      phn = fmaf(a.x, hv.x, fmaf(a.y, hv.y, fmaf(a.z, hv.z, fmaf(a.w, hv.w, phn))));
    }
    float sr = pxr + phr;          // r-gate needs only the sum
    float sz = pxz + phz;          // z-gate needs only the sum
    sr  += __shfl_xor(sr, 1);  sr  += __shfl_xor(sr, 2);
    sz  += __shfl_xor(sz, 1);  sz  += __shfl_xor(sz, 2);
    pxn += __shfl_xor(pxn, 1); pxn += __shfl_xor(pxn, 2);
    phn += __shfl_xor(phn, 1); phn += __shfl_xor(phn, 2);
    if (l4 == 0) {
      Ar[row] = sr  + bih[row]         + bhh[row];
      Az[row] = sz  + bih[row + H]     + bhh[row + H];
      Cn[row] = pxn + bih[row + 2 * H];
      Dn[row] = phn + bhh[row + 2 * H];
    }
  }
  __syncthreads();

  // ---- final: GRU cell ----
  const float rg = 1.f / (1.f + __expf(-Ar[tid]));
  const float zg = 1.f / (1.f + __expf(-Az[tid]));
  const float ng = tanhf(Cn[tid] + rg * Dn[tid]);
  const float hv = (1.f - zg) * ng + zg * hid[tid];
  hnew[(size_t)b * H + tid] = hv;
  hnewb[(size_t)b * H + tid] = bf1(hv);
}

// ---------------------------------------------------------------------------
// K3: logits = h_new @ out_W^T + out_b via bf16 MFMA 16x16x32, PLUS
// in-register LSE partials per (row, block) so the old k_lse (full 16.4 MB
// logits re-read) is eliminated. grid 250, block 256 (4 waves).
// Layouts (m89-verified): A[m=lane&15][k=quad*8+j]; C/D col=lane&15,
// row=quad*4+reg.
// ---------------------------------------------------------------------------
constexpr int LSTR = 72;   // shorts per LDS row (64 data + 8 pad) = 144 B
__global__ __launch_bounds__(256) void k_logits(
    const unsigned short* __restrict__ hnewb, const float* __restrict__ out_W,
    const float* __restrict__ out_b, float* __restrict__ logits,
    float2* __restrict__ lse_part) {
  const int tid = threadIdx.x;
  const int lane = tid & 63, wave = tid >> 6;
  const int v0 = blockIdx.x * 128;
  const int r16 = lane & 15, quad = lane >> 4;

  __shared__ __align__(16) short lA[128 * LSTR];
  __shared__ __align__(16) short lB[128 * LSTR];
  __shared__ float2 lred[4][128];   // per-wave (m,l) per row

  f32x4 acc[8][2];
  #pragma unroll
  for (int mt = 0; mt < 8; mt++) {
    acc[mt][0] = (f32x4){0.f, 0.f, 0.f, 0.f};
    acc[mt][1] = (f32x4){0.f, 0.f, 0.f, 0.f};
  }

  for (int k0 = 0; k0 < H; k0 += 64) {
    // stage A (already bf16): 128 rows x 64 shorts
    #pragma unroll
    for (int q = 0; q < 4; q++) {
      int idx = q * 256 + tid;            // 0..1023
      int row = idx >> 3, c8 = idx & 7;   // 8-short groups
      f32x4 v = *(const f32x4*)(hnewb + (size_t)row * H + k0 + c8 * 8);
      *(f32x4*)(&lA[row * LSTR + c8 * 8]) = v;
    }
    // stage B with fp32->bf16 convert: 128 rows x 64 floats
    #pragma unroll
    for (int q = 0; q < 8; q++) {
      int idx = q * 256 + tid;            // 0..2047
      int row = idx >> 4, c4 = idx & 15;  // float4 groups
      f32x4 wv = *(const f32x4*)(out_W + (size_t)(v0 + row) * H + k0 + c4 * 4);
      uint2 p;
      p.x = bfpack2(wv.x, wv.y);
      p.y = bfpack2(wv.z, wv.w);
      *(uint2*)(&lB[row * LSTR + c4 * 4]) = p;
    }
    __syncthreads();
    #pragma unroll
    for (int ks = 0; ks < 2; ks++) {
      short8 bf[2];
      #pragma unroll
      for (int nt = 0; nt < 2; nt++) {
        int row = wave * 32 + nt * 16 + r16;
        bf[nt] = *(const short8*)(&lB[row * LSTR + ks * 32 + quad * 8]);
      }
      #pragma unroll
      for (int mt = 0; mt < 8; mt++) {
        short8 af = *(const short8*)(&lA[(mt * 16 + r16) * LSTR + ks * 32 + quad * 8]);
        acc[mt][0] = __builtin_amdgcn_mfma_f32_16x16x32_bf16(af, bf[0], acc[mt][0], 0, 0, 0);
        acc[mt][1] = __builtin_amdgcn_mfma_f32_16x16x32_bf16(af, bf[1], acc[mt][1], 0, 0, 0);
      }
    }
    __syncthreads();
  }

  // epilogue: bias + store + per-quad (m,l) butterflies over the wave's
  // 32 columns per row; cross-wave merge in LDS.
  const int col0 = v0 + wave * 32 + r16;
  const float bias0 = out_b[col0];
  const float bias1 = out_b[col0 + 16];
  #pragma unroll
  for (int mt = 0; mt < 8; mt++) {
    #pragma unroll
    for (int r = 0; r < 4; r++) {
      const int brow = mt * 16 + quad * 4 + r;
      float a0 = acc[mt][0][r] + bias0;
      float a1 = acc[mt][1][r] + bias1;
      logits[(size_t)brow * V + col0]      = a0;
      logits[(size_t)brow * V + col0 + 16] = a1;
      float mv = fmaxf(a0, a1);
      #pragma unroll
      for (int off = 1; off < 16; off <<= 1) mv = fmaxf(mv, __shfl_xor(mv, off));
      float lv = __expf(a0 - mv) + __expf(a1 - mv);
      #pragma unroll
      for (int off = 1; off < 16; off <<= 1) lv += __shfl_xor(lv, off);
      if (r16 == 0) lred[wave][brow] = make_float2(mv, lv);
    }
  }
  __syncthreads();
  if (tid < 128) {
    float2 p = lred[0][tid];
    float M = p.x, L = p.y;
    #pragma unroll
    for (int w2 = 1; w2 < 4; w2++) {
      float2 q = lred[w2][tid];
      float nm = fmaxf(M, q.x);
      L = L * __expf(M - nm) + q.y * __expf(q.x - nm);
      M = nm;
    }
    lse_part[(size_t)tid * NBLK + blockIdx.x] = make_float2(M, L);
  }
}

// ---------------------------------------------------------------------------
// K4: merge the 250 per-block LSE partials -> lse[b] (scalar). grid B.
// ---------------------------------------------------------------------------
__global__ __launch_bounds__(256) void k_lsefin(
    const float2* __restrict__ lse_part, float* __restrict__ lse) {
  const int b = blockIdx.x, tid = threadIdx.x;
  const int lane = tid & 63, wave = tid >> 6;
  float m = -1e30f, l = 0.f;
  if (tid < NBLK) {
    float2 p = lse_part[(size_t)b * NBLK + tid];
    m = p.x; l = p.y;
  }
  #pragma unroll
  for (int off = 1; off < 64; off <<= 1) {
    float mo = __shfl_xor(m, off), lo = __shfl_xor(l, off);
    float nm = fmaxf(m, mo);
    l = l * __expf(m - nm) + lo * __expf(mo - nm);
    m = nm;
  }
  __shared__ float sm[4], sl[4];
  if (lane == 0) { sm[wave] = m; sl[wave] = l; }
  __syncthreads();
  if (tid == 0) {
    float M = sm[0], L = sl[0];
    #pragma unroll
    for (int w2 = 1; w2 < 4; w2++) {
      float nm = fmaxf(M, sm[w2]);
      L = L * __expf(M - nm) + sl[w2] * __expf(sm[w2] - nm);
      M = nm;
    }
    lse[b] = M + logf(L);
  }
}

// ---------------------------------------------------------------------------
// K5: logp = logits - lse[b] (in place, float4). grid (32, B).
// ---------------------------------------------------------------------------
__global__ __launch_bounds__(256) void k_sub(
    float* __restrict__ logits, const float* __restrict__ lse) {
  const int b = blockIdx.y;
  const int i = blockIdx.x * 256 + threadIdx.x;   // float4 index
  const float ls = lse[b];
  if (i < V / 4) {
    float4* p = (float4*)(logits + (size_t)b * V) + i;
    float4 x = *p;
    x.x -= ls; x.y -= ls; x.z -= ls; x.w -= ls;
    *p = x;
  }
}

// ---------------------------------------------------------------------------
extern "C" void kernel_launch(void* const* d_in, const int* in_sizes, int n_in,
                              void* d_out, int out_size, void* d_ws, size_t ws_size,
                              hipStream_t stream) {
  const int*   tokens = (const int*)d_in[0];
  const float* hidden = (const float*)d_in[1];
  const float* enc    = (const float*)d_in[2];
  const float* emb    = (const float*)d_in[3];
  const float* attn_W = (const float*)d_in[4];
  const float* attn_b = (const float*)d_in[5];
  const float* comb_W = (const float*)d_in[6];
  const float* comb_b = (const float*)d_in[7];
  const float* Wih    = (const float*)d_in[8];
  const float* Whh    = (const float*)d_in[9];
  const float* bih    = (const float*)d_in[10];
  const float* bhh    = (const float*)d_in[11];
  const float* out_W  = (const float*)d_in[12];
  const float* out_b  = (const float*)d_in[13];

  float* out    = (float*)d_out;
  float* logp   = out;                                   // (1,B,V)
  float* hnew   = out + (size_t)Bb * V;                  // (1,B,H)
  float* attn_o = hnew + (size_t)Bb * H;                 // (B,T,1)
  float* ctx_o  = attn_o + (size_t)Bb * T;               // (1,B,H)

  // Workspace layout (<= previous verified session's footprint):
  //   scores   : B*T floats (1 MB) — dead after k_ctx_gru; k_logits'
  //              lse_part (B*NBLK float2 = 256 KB) aliases it.
  //   ctx_part : B*NPART*H floats (8 MB)
  //   hnewb    : B*H bf16 (64 KB)
  //   lse      : B floats (512 B)
  float* ws       = (float*)d_ws;
  float* scores   = ws;                                     // B*T
  float2* lse_part = (float2*)ws;                           // aliases scores
  float* ctx_part = ws + (size_t)Bb * T;                    // B*NPART*H
  unsigned short* hnewb = (unsigned short*)(ctx_part + (size_t)Bb * NPART * H);
  float* lse      = (float*)(hnewb + (size_t)Bb * H);       // B floats

  k_attn<<<dim3(SPLITS, Bb), 256, 0, stream>>>(enc, hidden, attn_W, attn_b, scores, ctx_part);
  k_ctx_gru<<<dim3(Bb), 256, 0, stream>>>(scores, ctx_part, attn_o, ctx_o,
                                          tokens, hidden, emb, comb_W, comb_b,
                                          Wih, Whh, bih, bhh, hnew, hnewb);
  k_logits<<<dim3(V / 128), 256, 0, stream>>>(hnewb, out_W, out_b, logp, lse_part);
  k_lsefin<<<dim3(Bb), 256, 0, stream>>>(lse_part, lse);
  k_sub<<<dim3(V / 1024 + 1, Bb), 256, 0, stream>>>(logp, lse);
}

// Round 4
// 493.375 us; speedup vs baseline: 1.0290x; 1.0129x over previous
//
#include <hip/hip_runtime.h>
#include <cstddef>

// Shapes
constexpr int H  = 256;
constexpr int Bb = 128;
constexpr int T  = 2048;
constexpr int V  = 32000;
constexpr int SPLITS = 16;          // T-chunks for attention pass
constexpr int TC = T / SPLITS;      // 128 timesteps per block (32 per wave)
constexpr int NPART = SPLITS * 4;   // 64 ctx partials per b (per wave)
constexpr int NBLK = V / 64;        // 500 logits blocks -> LSE partials per row

typedef __attribute__((ext_vector_type(8))) short short8;
typedef __attribute__((ext_vector_type(4))) float f32x4;

// round-to-nearest-even fp32 -> bf16 (inputs are finite)
__device__ __forceinline__ unsigned short bf1(float a) {
  unsigned u = __builtin_bit_cast(unsigned, a);
  return (unsigned short)((u + 0x7fffu + ((u >> 16) & 1u)) >> 16);
}
__device__ __forceinline__ unsigned bfpack2(float a, float b) {
  unsigned ua = __builtin_bit_cast(unsigned, a);
  unsigned ub = __builtin_bit_cast(unsigned, b);
  ua = (ua + 0x7fffu + ((ua >> 16) & 1u)) >> 16;
  ub = (ub + 0x7fffu + ((ub >> 16) & 1u)) & 0xffff0000u;
  return ua | ub;
}

// ---------------------------------------------------------------------------
// K1: fused scores + unnormalized ctx partials. One pass over enc (256 MB).
// grid (SPLITS, B), block 256 = 4 waves. Wave owns 32 consecutive t.
// HBM-bound by construction (per-CU: 1 MB load at 24.6 GB/s share = 41 us
// vs ~4 us VALU) — leave alone.
// ---------------------------------------------------------------------------
__global__ __launch_bounds__(256) void k_attn(
    const float* __restrict__ enc, const float* __restrict__ hidden,
    const float* __restrict__ attn_W, const float* __restrict__ attn_b,
    float* __restrict__ scores, float* __restrict__ ctx_part) {
  const int b = blockIdx.y, chunk = blockIdx.x;
  const int tid = threadIdx.x, lane = tid & 63, wave = tid >> 6;

  const float4 we = *(const float4*)(attn_W + H + lane * 4);
  const float4 wh = *(const float4*)(attn_W + lane * 4);
  const float4 hv = *(const float4*)(hidden + (size_t)b * H + lane * 4);

  float hb = fmaf(wh.x, hv.x, fmaf(wh.y, hv.y, fmaf(wh.z, hv.z, wh.w * hv.w)));
  #pragma unroll
  for (int off = 1; off < 64; off <<= 1) hb += __shfl_xor(hb, off);
  hb += attn_b[0];

  const int t0 = chunk * TC + wave * 32;
  const float* base = enc + (size_t)t0 * (Bb * H) + (size_t)b * H + lane * 4;

  float4 acc = {0.f, 0.f, 0.f, 0.f};
  for (int i = 0; i < 32; i += 4) {
    float4 e0 = *(const float4*)(base + (size_t)(i + 0) * (Bb * H));
    float4 e1 = *(const float4*)(base + (size_t)(i + 1) * (Bb * H));
    float4 e2 = *(const float4*)(base + (size_t)(i + 2) * (Bb * H));
    float4 e3 = *(const float4*)(base + (size_t)(i + 3) * (Bb * H));

    float p0 = fmaf(e0.x, we.x, fmaf(e0.y, we.y, fmaf(e0.z, we.z, e0.w * we.w)));
    float p1 = fmaf(e1.x, we.x, fmaf(e1.y, we.y, fmaf(e1.z, we.z, e1.w * we.w)));
    float p2 = fmaf(e2.x, we.x, fmaf(e2.y, we.y, fmaf(e2.z, we.z, e2.w * we.w)));
    float p3 = fmaf(e3.x, we.x, fmaf(e3.y, we.y, fmaf(e3.z, we.z, e3.w * we.w)));
    #pragma unroll
    for (int off = 1; off < 64; off <<= 1) {
      p0 += __shfl_xor(p0, off);
      p1 += __shfl_xor(p1, off);
      p2 += __shfl_xor(p2, off);
      p3 += __shfl_xor(p3, off);
    }
    float s0 = p0 + hb, s1 = p1 + hb, s2 = p2 + hb, s3 = p3 + hb;
    float w0 = __expf(s0), w1 = __expf(s1), w2 = __expf(s2), w3 = __expf(s3);

    acc.x = fmaf(w0, e0.x, fmaf(w1, e1.x, fmaf(w2, e2.x, fmaf(w3, e3.x, acc.x))));
    acc.y = fmaf(w0, e0.y, fmaf(w1, e1.y, fmaf(w2, e2.y, fmaf(w3, e3.y, acc.y))));
    acc.z = fmaf(w0, e0.z, fmaf(w1, e1.z, fmaf(w2, e2.z, fmaf(w3, e3.z, acc.z))));
    acc.w = fmaf(w0, e0.w, fmaf(w1, e1.w, fmaf(w2, e2.w, fmaf(w3, e3.w, acc.w))));

    if (lane == 0) {
      float4 sv = {s0, s1, s2, s3};
      *(float4*)(scores + (size_t)b * T + t0 + i) = sv;
    }
  }
  float* cp = ctx_part + ((size_t)b * NPART + chunk * 4 + wave) * H + lane * 4;
  *(float4*)cp = acc;
}

// ---------------------------------------------------------------------------
// K2: softmax -> attn_w + ctx, then emb/comb/ReLU/GRU fused. grid B,
// block 256 = 4 waves. Quad-split GEMVs (4 lanes/row, coalesced 64B
// segments). L2-BW-bound on ~2 MB weights/block; GEMM-ify is next-round
// candidate if this shows hot.
// ---------------------------------------------------------------------------
__global__ __launch_bounds__(256) void k_ctx_gru(
    const float* __restrict__ scores, const float* __restrict__ ctx_part,
    float* __restrict__ attn_o, float* __restrict__ ctx_o,
    const int* __restrict__ tokens, const float* __restrict__ hidden,
    const float* __restrict__ emb_table,
    const float* __restrict__ comb_W, const float* __restrict__ comb_b,
    const float* __restrict__ Wih, const float* __restrict__ Whh,
    const float* __restrict__ bih, const float* __restrict__ bhh,
    float* __restrict__ hnew, unsigned short* __restrict__ hnewb) {
  const int b = blockIdx.x, tid = threadIdx.x;
  const int lane = tid & 63, wave = tid >> 6;
  const int g4 = lane >> 2, l4 = lane & 3;   // quad-split: 16 rows x 4 lanes
  __shared__ float red[4];
  __shared__ float m_sh, l_sh;
  __shared__ __align__(16) float x2[2 * H];
  __shared__ __align__(16) float hid[H];
  __shared__ __align__(16) float xs[H];
  __shared__ float Ar[H], Az[H], Cn[H], Dn[H];

  // ---- phase A: softmax over scores + ctx combine ----
  const float* sb = scores + (size_t)b * T;
  float s[8];
  #pragma unroll
  for (int q = 0; q < 8; q++) s[q] = sb[tid + 256 * q];

  float mx = s[0];
  #pragma unroll
  for (int q = 1; q < 8; q++) mx = fmaxf(mx, s[q]);
  #pragma unroll
  for (int off = 1; off < 64; off <<= 1) mx = fmaxf(mx, __shfl_xor(mx, off));
  if (lane == 0) red[wave] = mx;
  __syncthreads();
  if (tid == 0) m_sh = fmaxf(fmaxf(red[0], red[1]), fmaxf(red[2], red[3]));
  __syncthreads();
  const float m = m_sh;

  float w[8];
  float ps = 0.f;
  #pragma unroll
  for (int q = 0; q < 8; q++) { w[q] = __expf(s[q] - m); ps += w[q]; }
  #pragma unroll
  for (int off = 1; off < 64; off <<= 1) ps += __shfl_xor(ps, off);
  __syncthreads();
  if (lane == 0) red[wave] = ps;
  __syncthreads();
  if (tid == 0) l_sh = red[0] + red[1] + red[2] + red[3];
  __syncthreads();
  const float inv = 1.f / l_sh;

  #pragma unroll
  for (int q = 0; q < 8; q++) attn_o[(size_t)b * T + tid + 256 * q] = w[q] * inv;

  float c = 0.f;
  for (int si = 0; si < NPART; si++)
    c += ctx_part[((size_t)b * NPART + si) * H + tid];
  const float cval = c * __expf(-m) * inv;
  ctx_o[(size_t)b * H + tid] = cval;

  // stage inputs for phase B/C
  x2[tid]     = emb_table[(size_t)tokens[b] * H + tid];
  x2[H + tid] = cval;
  hid[tid]    = hidden[(size_t)b * H + tid];
  __syncthreads();

  // ---- phase B: comb linear + ReLU (quad-split GEMV, K=512) ----
  #pragma unroll 1
  for (int batch = 0; batch < 4; batch++) {
    const int row = wave * 64 + batch * 16 + g4;
    const float* wr = comb_W + (size_t)row * (2 * H);
    float p = 0.f;
    #pragma unroll 8
    for (int i = 0; i < 32; i++) {
      const int o = i * 16 + l4 * 4;
      float4 wv = *(const float4*)(wr + o);
      float4 xv = *(const float4*)(x2 + o);   // 16-way broadcast groups: free
      p = fmaf(wv.x, xv.x, fmaf(wv.y, xv.y, fmaf(wv.z, xv.z, fmaf(wv.w, xv.w, p))));
    }
    p += __shfl_xor(p, 1);
    p += __shfl_xor(p, 2);
    if (l4 == 0) xs[row] = fmaxf(p + comb_b[row], 0.f);
  }
  __syncthreads();

  // ---- phase C: 6 GRU gate GEMVs (quad-split, K=256) ----
  #pragma unroll 1
  for (int batch = 0; batch < 4; batch++) {
    const int row = wave * 64 + batch * 16 + g4;
    const float* wxr = Wih + (size_t)row * H;
    const float* wxz = Wih + (size_t)(row + H) * H;
    const float* wxn = Wih + (size_t)(row + 2 * H) * H;
    const float* whr = Whh + (size_t)row * H;
    const float* whz = Whh + (size_t)(row + H) * H;
    const float* whn = Whh + (size_t)(row + 2 * H) * H;
    float pxr = 0.f, pxz = 0.f, pxn = 0.f, phr = 0.f, phz = 0.f, phn = 0.f;
    #pragma unroll 2
    for (int i = 0; i < 16; i++) {
      const int o = i * 16 + l4 * 4;
      float4 xv = *(const float4*)(xs + o);
      float4 hv = *(const float4*)(hid + o);
      float4 a;
      a = *(const float4*)(wxr + o);
      pxr = fmaf(a.x, xv.x, fmaf(a.y, xv.y, fmaf(a.z, xv.z, fmaf(a.w, xv.w, pxr))));
      a = *(const float4*)(wxz + o);
      pxz = fmaf(a.x, xv.x, fmaf(a.y, xv.y, fmaf(a.z, xv.z, fmaf(a.w, xv.w, pxz))));
      a = *(const float4*)(wxn + o);
      pxn = fmaf(a.x, xv.x, fmaf(a.y, xv.y, fmaf(a.z, xv.z, fmaf(a.w, xv.w, pxn))));
      a = *(const float4*)(whr + o);
      phr = fmaf(a.x, hv.x, fmaf(a.y, hv.y, fmaf(a.z, hv.z, fmaf(a.w, hv.w, phr))));
      a = *(const float4*)(whz + o);
      phz = fmaf(a.x, hv.x, fmaf(a.y, hv.y, fmaf(a.z, hv.z, fmaf(a.w, hv.w, phz))));
      a = *(const float4*)(whn + o);
      phn = fmaf(a.x, hv.x, fmaf(a.y, hv.y, fmaf(a.z, hv.z, fmaf(a.w, hv.w, phn))));
    }
    float sr = pxr + phr;          // r-gate needs only the sum
    float sz = pxz + phz;          // z-gate needs only the sum
    sr  += __shfl_xor(sr, 1);  sr  += __shfl_xor(sr, 2);
    sz  += __shfl_xor(sz, 1);  sz  += __shfl_xor(sz, 2);
    pxn += __shfl_xor(pxn, 1); pxn += __shfl_xor(pxn, 2);
    phn += __shfl_xor(phn, 1); phn += __shfl_xor(phn, 2);
    if (l4 == 0) {
      Ar[row] = sr  + bih[row]         + bhh[row];
      Az[row] = sz  + bih[row + H]     + bhh[row + H];
      Cn[row] = pxn + bih[row + 2 * H];
      Dn[row] = phn + bhh[row + 2 * H];
    }
  }
  __syncthreads();

  // ---- final: GRU cell ----
  const float rg = 1.f / (1.f + __expf(-Ar[tid]));
  const float zg = 1.f / (1.f + __expf(-Az[tid]));
  const float ng = tanhf(Cn[tid] + rg * Dn[tid]);
  const float hv = (1.f - zg) * ng + zg * hid[tid];
  hnew[(size_t)b * H + tid] = hv;
  hnewb[(size_t)b * H + tid] = bf1(hv);
}

// ---------------------------------------------------------------------------
// K3: logits = h_new @ out_W^T + out_b via bf16 MFMA 16x16x32, with LSE
// partials computed in-epilogue. grid 500 (64-col tiles), block 256 (4
// waves; wave owns 16 cols, all 128 b-rows). The narrower tile doubles
// blocks/CU vs the old 128-col version -> 2x the waves hiding the cold
// out_W read latency. LDS 32 KB (was 41).
// Layouts (m89-verified): A[m=lane&15][k=quad*8+j]; C/D col=lane&15,
// row=quad*4+reg.
// ---------------------------------------------------------------------------
constexpr int LSTR = 72;   // shorts per LDS row (64 data + 8 pad) = 144 B
__global__ __launch_bounds__(256) void k_logits(
    const unsigned short* __restrict__ hnewb, const float* __restrict__ out_W,
    const float* __restrict__ out_b, float* __restrict__ logits,
    float2* __restrict__ lse_part) {
  const int tid = threadIdx.x;
  const int lane = tid & 63, wave = tid >> 6;
  const int v0 = blockIdx.x * 64;
  const int r16 = lane & 15, quad = lane >> 4;

  __shared__ __align__(16) short lA[128 * LSTR];
  __shared__ __align__(16) short lB[64 * LSTR];
  __shared__ float2 lred[4][128];   // per-wave (m,l) per row

  f32x4 acc[8];
  #pragma unroll
  for (int mt = 0; mt < 8; mt++) acc[mt] = (f32x4){0.f, 0.f, 0.f, 0.f};

  for (int k0 = 0; k0 < H; k0 += 64) {
    // stage A (already bf16): 128 rows x 64 shorts
    #pragma unroll
    for (int q = 0; q < 4; q++) {
      int idx = q * 256 + tid;            // 0..1023
      int row = idx >> 3, c8 = idx & 7;   // 8-short groups
      f32x4 v = *(const f32x4*)(hnewb + (size_t)row * H + k0 + c8 * 8);
      *(f32x4*)(&lA[row * LSTR + c8 * 8]) = v;
    }
    // stage B with fp32->bf16 convert: 64 rows x 64 floats
    #pragma unroll
    for (int q = 0; q < 4; q++) {
      int idx = q * 256 + tid;            // 0..1023
      int row = idx >> 4, c4 = idx & 15;  // float4 groups
      f32x4 wv = *(const f32x4*)(out_W + (size_t)(v0 + row) * H + k0 + c4 * 4);
      uint2 p;
      p.x = bfpack2(wv.x, wv.y);
      p.y = bfpack2(wv.z, wv.w);
      *(uint2*)(&lB[row * LSTR + c4 * 4]) = p;
    }
    __syncthreads();
    #pragma unroll
    for (int ks = 0; ks < 2; ks++) {
      const int brow = wave * 16 + r16;
      short8 bf = *(const short8*)(&lB[brow * LSTR + ks * 32 + quad * 8]);
      #pragma unroll
      for (int mt = 0; mt < 8; mt++) {
        short8 af = *(const short8*)(&lA[(mt * 16 + r16) * LSTR + ks * 32 + quad * 8]);
        acc[mt] = __builtin_amdgcn_mfma_f32_16x16x32_bf16(af, bf, acc[mt], 0, 0, 0);
      }
    }
    __syncthreads();
  }

  // epilogue: bias + store + per-quad (m,l) butterflies over the wave's
  // 16 columns per row; cross-wave merge in LDS.
  const int col0 = v0 + wave * 16 + r16;
  const float bias0 = out_b[col0];
  #pragma unroll
  for (int mt = 0; mt < 8; mt++) {
    #pragma unroll
    for (int r = 0; r < 4; r++) {
      const int brow = mt * 16 + quad * 4 + r;
      float a0 = acc[mt][r] + bias0;
      logits[(size_t)brow * V + col0] = a0;
      float mv = a0;
      #pragma unroll
      for (int off = 1; off < 16; off <<= 1) mv = fmaxf(mv, __shfl_xor(mv, off));
      float lv = __expf(a0 - mv);
      #pragma unroll
      for (int off = 1; off < 16; off <<= 1) lv += __shfl_xor(lv, off);
      if (r16 == 0) lred[wave][brow] = make_float2(mv, lv);
    }
  }
  __syncthreads();
  if (tid < 128) {
    float2 p = lred[0][tid];
    float M = p.x, L = p.y;
    #pragma unroll
    for (int w2 = 1; w2 < 4; w2++) {
      float2 q = lred[w2][tid];
      float nm = fmaxf(M, q.x);
      L = L * __expf(M - nm) + q.y * __expf(q.x - nm);
      M = nm;
    }
    lse_part[(size_t)tid * NBLK + blockIdx.x] = make_float2(M, L);
  }
}

// ---------------------------------------------------------------------------
// K4 (k_lsefin folded in): each block merges the 500 per-tile LSE partials
// for its batch row (4 KB L2 read + butterfly, ~1 us), then does
// logp = logits - lse in place. grid (32, B).
// ---------------------------------------------------------------------------
__global__ __launch_bounds__(256) void k_sub(
    float* __restrict__ logits, const float2* __restrict__ lse_part) {
  const int b = blockIdx.y, tid = threadIdx.x;
  const int lane = tid & 63, wave = tid >> 6;

  // merge partials: each thread covers up to 2 of the 500
  const float2* pp = lse_part + (size_t)b * NBLK;
  float m = -1e30f, l = 0.f;
  if (tid < NBLK) { float2 p = pp[tid]; m = p.x; l = p.y; }
  if (tid + 256 < NBLK) {
    float2 p = pp[tid + 256];
    float nm = fmaxf(m, p.x);
    l = l * __expf(m - nm) + p.y * __expf(p.x - nm);
    m = nm;
  }
  #pragma unroll
  for (int off = 1; off < 64; off <<= 1) {
    float mo = __shfl_xor(m, off), lo = __shfl_xor(l, off);
    float nm = fmaxf(m, mo);
    l = l * __expf(m - nm) + lo * __expf(mo - nm);
    m = nm;
  }
  __shared__ float sm[4], sl[4];
  if (lane == 0) { sm[wave] = m; sl[wave] = l; }
  __syncthreads();
  float M = sm[0], L = sl[0];
  #pragma unroll
  for (int w2 = 1; w2 < 4; w2++) {
    float nm = fmaxf(M, sm[w2]);
    L = L * __expf(M - nm) + sl[w2] * __expf(sm[w2] - nm);
    M = nm;
  }
  const float ls = M + logf(L);

  const int i = blockIdx.x * 256 + tid;   // float4 index
  if (i < V / 4) {
    float4* p = (float4*)(logits + (size_t)b * V) + i;
    float4 x = *p;
    x.x -= ls; x.y -= ls; x.z -= ls; x.w -= ls;
    *p = x;
  }
}

// ---------------------------------------------------------------------------
extern "C" void kernel_launch(void* const* d_in, const int* in_sizes, int n_in,
                              void* d_out, int out_size, void* d_ws, size_t ws_size,
                              hipStream_t stream) {
  const int*   tokens = (const int*)d_in[0];
  const float* hidden = (const float*)d_in[1];
  const float* enc    = (const float*)d_in[2];
  const float* emb    = (const float*)d_in[3];
  const float* attn_W = (const float*)d_in[4];
  const float* attn_b = (const float*)d_in[5];
  const float* comb_W = (const float*)d_in[6];
  const float* comb_b = (const float*)d_in[7];
  const float* Wih    = (const float*)d_in[8];
  const float* Whh    = (const float*)d_in[9];
  const float* bih    = (const float*)d_in[10];
  const float* bhh    = (const float*)d_in[11];
  const float* out_W  = (const float*)d_in[12];
  const float* out_b  = (const float*)d_in[13];

  float* out    = (float*)d_out;
  float* logp   = out;                                   // (1,B,V)
  float* hnew   = out + (size_t)Bb * V;                  // (1,B,H)
  float* attn_o = hnew + (size_t)Bb * H;                 // (B,T,1)
  float* ctx_o  = attn_o + (size_t)Bb * T;               // (1,B,H)

  // Workspace layout:
  //   scores   : B*T floats (1 MB) — dead after k_ctx_gru; k_logits'
  //              lse_part (B*NBLK float2 = 512 KB) aliases it.
  //   ctx_part : B*NPART*H floats (8 MB)
  //   hnewb    : B*H bf16 (64 KB)
  float* ws       = (float*)d_ws;
  float* scores   = ws;                                     // B*T
  float2* lse_part = (float2*)ws;                           // aliases scores
  float* ctx_part = ws + (size_t)Bb * T;                    // B*NPART*H
  unsigned short* hnewb = (unsigned short*)(ctx_part + (size_t)Bb * NPART * H);

  k_attn<<<dim3(SPLITS, Bb), 256, 0, stream>>>(enc, hidden, attn_W, attn_b, scores, ctx_part);
  k_ctx_gru<<<dim3(Bb), 256, 0, stream>>>(scores, ctx_part, attn_o, ctx_o,
                                          tokens, hidden, emb, comb_W, comb_b,
                                          Wih, Whh, bih, bhh, hnew, hnewb);
  k_logits<<<dim3(V / 64), 256, 0, stream>>>(hnewb, out_W, out_b, logp, lse_part);
  k_sub<<<dim3(V / 1024 + 1, Bb), 256, 0, stream>>>(logp, lse_part);
}

// Round 5
// 479.538 us; speedup vs baseline: 1.0587x; 1.0289x over previous
//
#include <hip/hip_runtime.h>
#include <cstddef>

// Shapes
constexpr int H  = 256;
constexpr int Bb = 128;
constexpr int T  = 2048;
constexpr int V  = 32000;
constexpr int SPLITS = 8;           // T-chunks for attention pass
constexpr int TC = T / SPLITS;      // 256 timesteps per block (64 per wave)
constexpr int NPART = SPLITS * 4;   // 32 ctx partials per b (per wave)
constexpr int NBLK = V / 64;        // 500 logits blocks -> LSE partials per row

typedef __attribute__((ext_vector_type(8))) short short8;
typedef __attribute__((ext_vector_type(4))) float f32x4;

// round-to-nearest-even fp32 -> bf16 (inputs are finite)
__device__ __forceinline__ unsigned short bf1(float a) {
  unsigned u = __builtin_bit_cast(unsigned, a);
  return (unsigned short)((u + 0x7fffu + ((u >> 16) & 1u)) >> 16);
}
__device__ __forceinline__ unsigned bfpack2(float a, float b) {
  unsigned ua = __builtin_bit_cast(unsigned, a);
  unsigned ub = __builtin_bit_cast(unsigned, b);
  ua = (ua + 0x7fffu + ((ua >> 16) & 1u)) >> 16;
  ub = (ub + 0x7fffu + ((ub >> 16) & 1u)) & 0xffff0000u;
  return ua | ub;
}

// ---------------------------------------------------------------------------
// K1: fused scores + unnormalized ctx partials. One pass over enc (256 MB).
// grid (SPLITS, B), block 256 = 4 waves. Wave owns 64 consecutive t.
// HBM-bound by construction. SPLITS=8 halves ctx_part traffic vs 16 while
// keeping 1024 blocks (4/CU, 16 waves/CU >> BDP).
// ---------------------------------------------------------------------------
__global__ __launch_bounds__(256) void k_attn(
    const float* __restrict__ enc, const float* __restrict__ hidden,
    const float* __restrict__ attn_W, const float* __restrict__ attn_b,
    float* __restrict__ scores, float* __restrict__ ctx_part) {
  const int b = blockIdx.y, chunk = blockIdx.x;
  const int tid = threadIdx.x, lane = tid & 63, wave = tid >> 6;

  const float4 we = *(const float4*)(attn_W + H + lane * 4);
  const float4 wh = *(const float4*)(attn_W + lane * 4);
  const float4 hv = *(const float4*)(hidden + (size_t)b * H + lane * 4);

  float hb = fmaf(wh.x, hv.x, fmaf(wh.y, hv.y, fmaf(wh.z, hv.z, wh.w * hv.w)));
  #pragma unroll
  for (int off = 1; off < 64; off <<= 1) hb += __shfl_xor(hb, off);
  hb += attn_b[0];

  const int t0 = chunk * TC + wave * 64;
  const float* base = enc + (size_t)t0 * (Bb * H) + (size_t)b * H + lane * 4;

  float4 acc = {0.f, 0.f, 0.f, 0.f};
  for (int i = 0; i < 64; i += 4) {
    float4 e0 = *(const float4*)(base + (size_t)(i + 0) * (Bb * H));
    float4 e1 = *(const float4*)(base + (size_t)(i + 1) * (Bb * H));
    float4 e2 = *(const float4*)(base + (size_t)(i + 2) * (Bb * H));
    float4 e3 = *(const float4*)(base + (size_t)(i + 3) * (Bb * H));

    float p0 = fmaf(e0.x, we.x, fmaf(e0.y, we.y, fmaf(e0.z, we.z, e0.w * we.w)));
    float p1 = fmaf(e1.x, we.x, fmaf(e1.y, we.y, fmaf(e1.z, we.z, e1.w * we.w)));
    float p2 = fmaf(e2.x, we.x, fmaf(e2.y, we.y, fmaf(e2.z, we.z, e2.w * we.w)));
    float p3 = fmaf(e3.x, we.x, fmaf(e3.y, we.y, fmaf(e3.z, we.z, e3.w * we.w)));
    #pragma unroll
    for (int off = 1; off < 64; off <<= 1) {
      p0 += __shfl_xor(p0, off);
      p1 += __shfl_xor(p1, off);
      p2 += __shfl_xor(p2, off);
      p3 += __shfl_xor(p3, off);
    }
    float s0 = p0 + hb, s1 = p1 + hb, s2 = p2 + hb, s3 = p3 + hb;
    float w0 = __expf(s0), w1 = __expf(s1), w2 = __expf(s2), w3 = __expf(s3);

    acc.x = fmaf(w0, e0.x, fmaf(w1, e1.x, fmaf(w2, e2.x, fmaf(w3, e3.x, acc.x))));
    acc.y = fmaf(w0, e0.y, fmaf(w1, e1.y, fmaf(w2, e2.y, fmaf(w3, e3.y, acc.y))));
    acc.z = fmaf(w0, e0.z, fmaf(w1, e1.z, fmaf(w2, e2.z, fmaf(w3, e3.z, acc.z))));
    acc.w = fmaf(w0, e0.w, fmaf(w1, e1.w, fmaf(w2, e2.w, fmaf(w3, e3.w, acc.w))));

    if (lane == 0) {
      float4 sv = {s0, s1, s2, s3};
      *(float4*)(scores + (size_t)b * T + t0 + i) = sv;
    }
  }
  float* cp = ctx_part + ((size_t)b * NPART + chunk * 4 + wave) * H + lane * 4;
  *(float4*)cp = acc;
}

// ---------------------------------------------------------------------------
// K2: phase A only — exact softmax over scores -> attn_w; combine ctx
// partials -> ctx; materialize x2 = [emb | ctx] for the GEMV kernel.
// grid B, block 256 = 4 waves.
// ---------------------------------------------------------------------------
__global__ __launch_bounds__(256) void k_ctx(
    const float* __restrict__ scores, const float* __restrict__ ctx_part,
    const int* __restrict__ tokens, const float* __restrict__ emb_table,
    float* __restrict__ attn_o, float* __restrict__ ctx_o,
    float* __restrict__ x2buf) {
  const int b = blockIdx.x, tid = threadIdx.x;
  const int lane = tid & 63, wave = tid >> 6;
  __shared__ float red[4];
  __shared__ float m_sh, l_sh;

  const float* sb = scores + (size_t)b * T;
  float s[8];
  #pragma unroll
  for (int q = 0; q < 8; q++) s[q] = sb[tid + 256 * q];

  float mx = s[0];
  #pragma unroll
  for (int q = 1; q < 8; q++) mx = fmaxf(mx, s[q]);
  #pragma unroll
  for (int off = 1; off < 64; off <<= 1) mx = fmaxf(mx, __shfl_xor(mx, off));
  if (lane == 0) red[wave] = mx;
  __syncthreads();
  if (tid == 0) m_sh = fmaxf(fmaxf(red[0], red[1]), fmaxf(red[2], red[3]));
  __syncthreads();
  const float m = m_sh;

  float w[8];
  float ps = 0.f;
  #pragma unroll
  for (int q = 0; q < 8; q++) { w[q] = __expf(s[q] - m); ps += w[q]; }
  #pragma unroll
  for (int off = 1; off < 64; off <<= 1) ps += __shfl_xor(ps, off);
  __syncthreads();
  if (lane == 0) red[wave] = ps;
  __syncthreads();
  if (tid == 0) l_sh = red[0] + red[1] + red[2] + red[3];
  __syncthreads();
  const float inv = 1.f / l_sh;

  #pragma unroll
  for (int q = 0; q < 8; q++) attn_o[(size_t)b * T + tid + 256 * q] = w[q] * inv;

  float c = 0.f;
  for (int si = 0; si < NPART; si++)
    c += ctx_part[((size_t)b * NPART + si) * H + tid];
  const float cval = c * __expf(-m) * inv;
  ctx_o[(size_t)b * H + tid] = cval;

  x2buf[(size_t)b * (2 * H) + tid]     = emb_table[(size_t)tokens[b] * H + tid];
  x2buf[(size_t)b * (2 * H) + H + tid] = cval;
}

// ---------------------------------------------------------------------------
// K3: comb linear + ReLU + half of the GRU gate GEMVs + cell.
// grid (B, 2), block 256 = 4 waves. Block (b,h): full xs (phase C needs the
// complete vector as input, so comb is duplicated across h — 512 KB), but
// only half of the 6 gate GEMVs (384 KB). Per-CU weight bytes 2 MB -> 1.25
// MB and active CUs 128 -> 256 vs the old fused kernel.
// Quad-split GEMVs: 4 lanes/row, coalesced 64B segments, 2-stage shfl.
// ---------------------------------------------------------------------------
__global__ __launch_bounds__(256) void k_gru(
    const float* __restrict__ x2buf, const float* __restrict__ hidden,
    const float* __restrict__ comb_W, const float* __restrict__ comb_b,
    const float* __restrict__ Wih, const float* __restrict__ Whh,
    const float* __restrict__ bih, const float* __restrict__ bhh,
    float* __restrict__ hnew, unsigned short* __restrict__ hnewb) {
  const int b = blockIdx.x, h = blockIdx.y, tid = threadIdx.x;
  const int lane = tid & 63, wave = tid >> 6;
  const int g4 = lane >> 2, l4 = lane & 3;   // quad-split: 16 rows x 4 lanes
  __shared__ __align__(16) float x2[2 * H];
  __shared__ __align__(16) float hid[H];
  __shared__ __align__(16) float xs[H];
  __shared__ float Ar[128], Az[128], Cn[128], Dn[128];

  x2[tid]     = x2buf[(size_t)b * (2 * H) + tid];
  x2[H + tid] = x2buf[(size_t)b * (2 * H) + H + tid];
  hid[tid]    = hidden[(size_t)b * H + tid];
  __syncthreads();

  // ---- phase B: comb linear + ReLU (full 256 rows; quad-split, K=512) ----
  #pragma unroll 1
  for (int batch = 0; batch < 4; batch++) {
    const int row = wave * 64 + batch * 16 + g4;
    const float* wr = comb_W + (size_t)row * (2 * H);
    float p = 0.f;
    #pragma unroll 8
    for (int i = 0; i < 32; i++) {
      const int o = i * 16 + l4 * 4;
      float4 wv = *(const float4*)(wr + o);
      float4 xv = *(const float4*)(x2 + o);   // 16-way broadcast groups: free
      p = fmaf(wv.x, xv.x, fmaf(wv.y, xv.y, fmaf(wv.z, xv.z, fmaf(wv.w, xv.w, p))));
    }
    p += __shfl_xor(p, 1);
    p += __shfl_xor(p, 2);
    if (l4 == 0) xs[row] = fmaxf(p + comb_b[row], 0.f);
  }
  __syncthreads();

  // ---- phase C: this block's half of the 6 gate GEMVs (quad-split) ----
  #pragma unroll 1
  for (int batch = 0; batch < 2; batch++) {
    const int rl  = wave * 32 + batch * 16 + g4;  // local row 0..127
    const int row = h * 128 + rl;                 // global gate row 0..255
    const float* wxr = Wih + (size_t)row * H;
    const float* wxz = Wih + (size_t)(row + H) * H;
    const float* wxn = Wih + (size_t)(row + 2 * H) * H;
    const float* whr = Whh + (size_t)row * H;
    const float* whz = Whh + (size_t)(row + H) * H;
    const float* whn = Whh + (size_t)(row + 2 * H) * H;
    float pxr = 0.f, pxz = 0.f, pxn = 0.f, phr = 0.f, phz = 0.f, phn = 0.f;
    #pragma unroll 2
    for (int i = 0; i < 16; i++) {
      const int o = i * 16 + l4 * 4;
      float4 xv = *(const float4*)(xs + o);
      float4 hv = *(const float4*)(hid + o);
      float4 a;
      a = *(const float4*)(wxr + o);
      pxr = fmaf(a.x, xv.x, fmaf(a.y, xv.y, fmaf(a.z, xv.z, fmaf(a.w, xv.w, pxr))));
      a = *(const float4*)(wxz + o);
      pxz = fmaf(a.x, xv.x, fmaf(a.y, xv.y, fmaf(a.z, xv.z, fmaf(a.w, xv.w, pxz))));
      a = *(const float4*)(wxn + o);
      pxn = fmaf(a.x, xv.x, fmaf(a.y, xv.y, fmaf(a.z, xv.z, fmaf(a.w, xv.w, pxn))));
      a = *(const float4*)(whr + o);
      phr = fmaf(a.x, hv.x, fmaf(a.y, hv.y, fmaf(a.z, hv.z, fmaf(a.w, hv.w, phr))));
      a = *(const float4*)(whz + o);
      phz = fmaf(a.x, hv.x, fmaf(a.y, hv.y, fmaf(a.z, hv.z, fmaf(a.w, hv.w, phz))));
      a = *(const float4*)(whn + o);
      phn = fmaf(a.x, hv.x, fmaf(a.y, hv.y, fmaf(a.z, hv.z, fmaf(a.w, hv.w, phn))));
    }
    float sr = pxr + phr;          // r-gate needs only the sum
    float sz = pxz + phz;          // z-gate needs only the sum
    sr  += __shfl_xor(sr, 1);  sr  += __shfl_xor(sr, 2);
    sz  += __shfl_xor(sz, 1);  sz  += __shfl_xor(sz, 2);
    pxn += __shfl_xor(pxn, 1); pxn += __shfl_xor(pxn, 2);
    phn += __shfl_xor(phn, 1); phn += __shfl_xor(phn, 2);
    if (l4 == 0) {
      Ar[rl] = sr  + bih[row]         + bhh[row];
      Az[rl] = sz  + bih[row + H]     + bhh[row + H];
      Cn[rl] = pxn + bih[row + 2 * H];
      Dn[rl] = phn + bhh[row + 2 * H];
    }
  }
  __syncthreads();

  // ---- GRU cell for this half ----
  if (tid < 128) {
    const int row = h * 128 + tid;
    const float rg = 1.f / (1.f + __expf(-Ar[tid]));
    const float zg = 1.f / (1.f + __expf(-Az[tid]));
    const float ng = tanhf(Cn[tid] + rg * Dn[tid]);
    const float hv = (1.f - zg) * ng + zg * hid[row];
    hnew[(size_t)b * H + row] = hv;
    hnewb[(size_t)b * H + row] = bf1(hv);
  }
}

// ---------------------------------------------------------------------------
// K4: logits = h_new @ out_W^T + out_b via bf16 MFMA 16x16x32, with LSE
// partials computed in-epilogue. grid 500 (64-col tiles), block 256 (4
// waves; wave owns 16 cols, all 128 b-rows).
// Layouts (m89-verified): A[m=lane&15][k=quad*8+j]; C/D col=lane&15,
// row=quad*4+reg.
// ---------------------------------------------------------------------------
constexpr int LSTR = 72;   // shorts per LDS row (64 data + 8 pad) = 144 B
__global__ __launch_bounds__(256) void k_logits(
    const unsigned short* __restrict__ hnewb, const float* __restrict__ out_W,
    const float* __restrict__ out_b, float* __restrict__ logits,
    float2* __restrict__ lse_part) {
  const int tid = threadIdx.x;
  const int lane = tid & 63, wave = tid >> 6;
  const int v0 = blockIdx.x * 64;
  const int r16 = lane & 15, quad = lane >> 4;

  __shared__ __align__(16) short lA[128 * LSTR];
  __shared__ __align__(16) short lB[64 * LSTR];
  __shared__ float2 lred[4][128];   // per-wave (m,l) per row

  f32x4 acc[8];
  #pragma unroll
  for (int mt = 0; mt < 8; mt++) acc[mt] = (f32x4){0.f, 0.f, 0.f, 0.f};

  for (int k0 = 0; k0 < H; k0 += 64) {
    // stage A (already bf16): 128 rows x 64 shorts
    #pragma unroll
    for (int q = 0; q < 4; q++) {
      int idx = q * 256 + tid;            // 0..1023
      int row = idx >> 3, c8 = idx & 7;   // 8-short groups
      f32x4 v = *(const f32x4*)(hnewb + (size_t)row * H + k0 + c8 * 8);
      *(f32x4*)(&lA[row * LSTR + c8 * 8]) = v;
    }
    // stage B with fp32->bf16 convert: 64 rows x 64 floats
    #pragma unroll
    for (int q = 0; q < 4; q++) {
      int idx = q * 256 + tid;            // 0..1023
      int row = idx >> 4, c4 = idx & 15;  // float4 groups
      f32x4 wv = *(const f32x4*)(out_W + (size_t)(v0 + row) * H + k0 + c4 * 4);
      uint2 p;
      p.x = bfpack2(wv.x, wv.y);
      p.y = bfpack2(wv.z, wv.w);
      *(uint2*)(&lB[row * LSTR + c4 * 4]) = p;
    }
    __syncthreads();
    #pragma unroll
    for (int ks = 0; ks < 2; ks++) {
      const int brow = wave * 16 + r16;
      short8 bf = *(const short8*)(&lB[brow * LSTR + ks * 32 + quad * 8]);
      #pragma unroll
      for (int mt = 0; mt < 8; mt++) {
        short8 af = *(const short8*)(&lA[(mt * 16 + r16) * LSTR + ks * 32 + quad * 8]);
        acc[mt] = __builtin_amdgcn_mfma_f32_16x16x32_bf16(af, bf, acc[mt], 0, 0, 0);
      }
    }
    __syncthreads();
  }

  // epilogue: bias + store + per-quad (m,l) butterflies over the wave's
  // 16 columns per row; cross-wave merge in LDS.
  const int col0 = v0 + wave * 16 + r16;
  const float bias0 = out_b[col0];
  #pragma unroll
  for (int mt = 0; mt < 8; mt++) {
    #pragma unroll
    for (int r = 0; r < 4; r++) {
      const int brow = mt * 16 + quad * 4 + r;
      float a0 = acc[mt][r] + bias0;
      logits[(size_t)brow * V + col0] = a0;
      float mv = a0;
      #pragma unroll
      for (int off = 1; off < 16; off <<= 1) mv = fmaxf(mv, __shfl_xor(mv, off));
      float lv = __expf(a0 - mv);
      #pragma unroll
      for (int off = 1; off < 16; off <<= 1) lv += __shfl_xor(lv, off);
      if (r16 == 0) lred[wave][brow] = make_float2(mv, lv);
    }
  }
  __syncthreads();
  if (tid < 128) {
    float2 p = lred[0][tid];
    float M = p.x, L = p.y;
    #pragma unroll
    for (int w2 = 1; w2 < 4; w2++) {
      float2 q = lred[w2][tid];
      float nm = fmaxf(M, q.x);
      L = L * __expf(M - nm) + q.y * __expf(q.x - nm);
      M = nm;
    }
    lse_part[(size_t)tid * NBLK + blockIdx.x] = make_float2(M, L);
  }
}

// ---------------------------------------------------------------------------
// K5: each block merges the 500 per-tile LSE partials for its batch row
// (4 KB L2 read + butterfly), then logp = logits - lse in place. grid (32,B).
// ---------------------------------------------------------------------------
__global__ __launch_bounds__(256) void k_sub(
    float* __restrict__ logits, const float2* __restrict__ lse_part) {
  const int b = blockIdx.y, tid = threadIdx.x;
  const int lane = tid & 63, wave = tid >> 6;

  // merge partials: each thread covers up to 2 of the 500
  const float2* pp = lse_part + (size_t)b * NBLK;
  float m = -1e30f, l = 0.f;
  if (tid < NBLK) { float2 p = pp[tid]; m = p.x; l = p.y; }
  if (tid + 256 < NBLK) {
    float2 p = pp[tid + 256];
    float nm = fmaxf(m, p.x);
    l = l * __expf(m - nm) + p.y * __expf(p.x - nm);
    m = nm;
  }
  #pragma unroll
  for (int off = 1; off < 64; off <<= 1) {
    float mo = __shfl_xor(m, off), lo = __shfl_xor(l, off);
    float nm = fmaxf(m, mo);
    l = l * __expf(m - nm) + lo * __expf(mo - nm);
    m = nm;
  }
  __shared__ float sm[4], sl[4];
  if (lane == 0) { sm[wave] = m; sl[wave] = l; }
  __syncthreads();
  float M = sm[0], L = sl[0];
  #pragma unroll
  for (int w2 = 1; w2 < 4; w2++) {
    float nm = fmaxf(M, sm[w2]);
    L = L * __expf(M - nm) + sl[w2] * __expf(sm[w2] - nm);
    M = nm;
  }
  const float ls = M + logf(L);

  const int i = blockIdx.x * 256 + tid;   // float4 index
  if (i < V / 4) {
    float4* p = (float4*)(logits + (size_t)b * V) + i;
    float4 x = *p;
    x.x -= ls; x.y -= ls; x.z -= ls; x.w -= ls;
    *p = x;
  }
}

// ---------------------------------------------------------------------------
extern "C" void kernel_launch(void* const* d_in, const int* in_sizes, int n_in,
                              void* d_out, int out_size, void* d_ws, size_t ws_size,
                              hipStream_t stream) {
  const int*   tokens = (const int*)d_in[0];
  const float* hidden = (const float*)d_in[1];
  const float* enc    = (const float*)d_in[2];
  const float* emb    = (const float*)d_in[3];
  const float* attn_W = (const float*)d_in[4];
  const float* attn_b = (const float*)d_in[5];
  const float* comb_W = (const float*)d_in[6];
  const float* comb_b = (const float*)d_in[7];
  const float* Wih    = (const float*)d_in[8];
  const float* Whh    = (const float*)d_in[9];
  const float* bih    = (const float*)d_in[10];
  const float* bhh    = (const float*)d_in[11];
  const float* out_W  = (const float*)d_in[12];
  const float* out_b  = (const float*)d_in[13];

  float* out    = (float*)d_out;
  float* logp   = out;                                   // (1,B,V)
  float* hnew   = out + (size_t)Bb * V;                  // (1,B,H)
  float* attn_o = hnew + (size_t)Bb * H;                 // (B,T,1)
  float* ctx_o  = attn_o + (size_t)Bb * T;               // (1,B,H)

  // Workspace layout:
  //   scores   : B*T floats (1 MB) — dead after k_ctx; k_logits' lse_part
  //              (B*NBLK float2 = 512 KB) aliases it.
  //   ctx_part : B*NPART*H floats (4 MB)
  //   x2buf    : B*2H floats (256 KB)
  //   hnewb    : B*H bf16 (64 KB)
  float* ws       = (float*)d_ws;
  float* scores   = ws;                                     // B*T
  float2* lse_part = (float2*)ws;                           // aliases scores
  float* ctx_part = ws + (size_t)Bb * T;                    // B*NPART*H
  float* x2buf    = ctx_part + (size_t)Bb * NPART * H;      // B*2H
  unsigned short* hnewb = (unsigned short*)(x2buf + (size_t)Bb * 2 * H);

  k_attn<<<dim3(SPLITS, Bb), 256, 0, stream>>>(enc, hidden, attn_W, attn_b, scores, ctx_part);
  k_ctx<<<dim3(Bb), 256, 0, stream>>>(scores, ctx_part, tokens, emb, attn_o, ctx_o, x2buf);
  k_gru<<<dim3(Bb, 2), 256, 0, stream>>>(x2buf, hidden, comb_W, comb_b,
                                         Wih, Whh, bih, bhh, hnew, hnewb);
  k_logits<<<dim3(V / 64), 256, 0, stream>>>(hnewb, out_W, out_b, logp, lse_part);
  k_sub<<<dim3(V / 1024 + 1, Bb), 256, 0, stream>>>(logp, lse_part);
}